// Round 1
// baseline (220.962 us; speedup 1.0000x reference)
//
#include <hip/hip_runtime.h>

typedef __attribute__((ext_vector_type(8))) __bf16 bf16x8;
typedef __attribute__((ext_vector_type(4))) float f32x4;
typedef unsigned short u16;
typedef unsigned int u32;

#define MFMA16(a, b, c) __builtin_amdgcn_mfma_f32_16x16x32_bf16((a), (b), (c), 0, 0, 0)

__device__ __forceinline__ u16 f2bf(float f) {
  return (u16)((__float_as_uint(f) + 0x8000u) >> 16);
}

// dims
#define BDIM 2
#define SDIM 2048
#define EDIM 1024
#define HDIM 16
#define HD 64
#define MDIM (BDIM * SDIM)  // 4096

// q pre-scale: 0.125 * log2(e), folded into q at the QKV-GEMM epilogue
#define SC_C1 0.1803368801111355f

typedef __attribute__((address_space(3))) void lds_void;
typedef __attribute__((address_space(1))) void g_void;

__device__ __forceinline__ void async_lds16(const void* g, void* lds_byte) {
  __builtin_amdgcn_global_load_lds((const g_void*)g, (lds_void*)lds_byte, 16, 0, 0);
}

// ===================== cvt3: three f32 -> bf16 arrays, one launch ==========
__global__ __launch_bounds__(256) void cvt3_kernel(
    const float* __restrict__ s0, u16* __restrict__ d0, int n0,
    const float* __restrict__ s1, u16* __restrict__ d1, int n1,
    const float* __restrict__ s2, u16* __restrict__ d2, int n2) {
  int i = (blockIdx.x * 256 + threadIdx.x) * 8;
  const float* s;
  u16* d;
  if (i < n0) {
    s = s0 + i; d = d0 + i;
  } else if (i < n0 + n1) {
    s = s1 + (i - n0); d = d1 + (i - n0);
  } else if (i < n0 + n1 + n2) {
    s = s2 + (i - n0 - n1); d = d2 + (i - n0 - n1);
  } else {
    return;
  }
  float4 f0 = *(const float4*)(s);
  float4 f1 = *(const float4*)(s + 4);
  union { uint4 u; u16 h[8]; } o;
  o.h[0] = f2bf(f0.x); o.h[1] = f2bf(f0.y); o.h[2] = f2bf(f0.z); o.h[3] = f2bf(f0.w);
  o.h[4] = f2bf(f1.x); o.h[5] = f2bf(f1.y); o.h[6] = f2bf(f1.z); o.h[7] = f2bf(f1.w);
  *(uint4*)(d) = o.u;
}

// ===================== GEMM1: QKV projection (128x128 tile, BK=64) ====
// out: q bf16 [B][H][S][HD] PRE-SCALED by SC_C1; k bf16 [B][H][S][HD];
//      v bf16 TRANSPOSED [B][H][HD][S]
__global__ __launch_bounds__(256) void gemm_qkv_kernel(
    const u16* __restrict__ X, const u16* __restrict__ W,
    const float* __restrict__ bias, u16* __restrict__ qb,
    u16* __restrict__ kb, u16* __restrict__ vtb) {
  __shared__ __align__(16) u16 As[128 * 64];
  __shared__ __align__(16) u16 Bs[128 * 64];
  const int m0 = blockIdx.x * 128, n0 = blockIdx.y * 128;
  const bool isV = (n0 >= 2 * EDIM);
  const int t = threadIdx.x;
  const int l = t & 63;
  const int quad = l >> 4, col = l & 15;
  const int wid = t >> 6;
  const int mh = wid & 1, nh = wid >> 1;
  const int wofs = (t & 192) << 4;  // wave_id * 1024 bytes
  f32x4 acc[4][4] = {};
  const u16* Ab = X + (size_t)m0 * EDIM;
  const u16* Bb = W + (size_t)n0 * EDIM;
  char* AsB = (char*)As;
  char* BsB = (char*)Bs;

  for (int k0 = 0; k0 < EDIM; k0 += 64) {
    __syncthreads();
#pragma unroll
    for (int p = 0; p < 4; p++) {
      int idx = p * 256 + t;       // 0..1023
      int row = idx >> 3;          // 0..127
      int gch = (idx & 7) ^ (row & 7);
      async_lds16(Ab + (size_t)row * EDIM + k0 + gch * 8, AsB + p * 4096 + wofs);
      async_lds16(Bb + (size_t)row * EDIM + k0 + gch * 8, BsB + p * 4096 + wofs);
    }
    __syncthreads();
#pragma unroll
    for (int kk = 0; kk < 2; kk++) {
      bf16x8 af[4], bfr[4];
#pragma unroll
      for (int i = 0; i < 4; i++) {
        int ra = 64 * mh + 16 * i + col;
        af[i] = *(const bf16x8*)&As[ra * 64 + (((kk * 4 + quad) ^ (ra & 7)) * 8)];
        int rb = 64 * nh + 16 * i + col;
        bfr[i] = *(const bf16x8*)&Bs[rb * 64 + (((kk * 4 + quad) ^ (rb & 7)) * 8)];
      }
      if (isV) {
#pragma unroll
        for (int i = 0; i < 4; i++)
#pragma unroll
          for (int j = 0; j < 4; j++)
            acc[i][j] = MFMA16(bfr[i], af[j], acc[i][j]);  // rows = W features
      } else {
#pragma unroll
        for (int i = 0; i < 4; i++)
#pragma unroll
          for (int j = 0; j < 4; j++)
            acc[i][j] = MFMA16(af[i], bfr[j], acc[i][j]);  // rows = tokens
      }
    }
  }

  if (isV) {
#pragma unroll
    for (int i = 0; i < 4; i++)
#pragma unroll
      for (int j = 0; j < 4; j++)
#pragma unroll
        for (int r = 0; r < 4; r++) {
          int n = n0 + 64 * nh + 16 * i + quad * 4 + r;  // feature (2048..3071)
          int m = m0 + 64 * mh + 16 * j + col;           // token
          float val = acc[i][j][r] + bias[n];
          int e = n & 1023;
          int hh = e >> 6, d = e & 63;
          int bb = m >> 11, s = m & 2047;
          vtb[(((size_t)(bb * HDIM + hh)) * HD + d) * SDIM + s] = f2bf(val);
        }
  } else {
    const float qscale = (n0 < EDIM) ? SC_C1 : 1.0f;  // block-uniform
#pragma unroll
    for (int i = 0; i < 4; i++)
#pragma unroll
      for (int j = 0; j < 4; j++)
#pragma unroll
        for (int r = 0; r < 4; r++) {
          int m = m0 + 64 * mh + 16 * i + quad * 4 + r;
          int n = n0 + 64 * nh + 16 * j + col;
          float val = (acc[i][j][r] + bias[n]) * qscale;
          int which = n >> 10, e = n & 1023;
          int hh = e >> 6, d = e & 63;
          int bb = m >> 11, s = m & 2047;
          u16* dst = (which == 0) ? qb : kb;
          dst[(((size_t)(bb * HDIM + hh)) * SDIM + s) * HD + d] = f2bf(val);
        }
  }
}

// ===================== Attention: pipelined flash, exp2-only softmax ======
// SWAPPED QK^T: S-scores computed as mfma(K, Q) so each lane holds one q
// (col = lane&15) and 16 consecutive-in-r k values. P pairs packed with
// v_cvt_pk_bf16_f32 and stored with 4x ds_write_b64 (was 16x ds_write_b16).
// K dbuf x2, V dbuf x2 (stage t+1), Ps 64x64 swizzled.
// LDS = 16K + 16K + 8K = 40960 B -> exactly 4 blocks/CU.
__global__ __launch_bounds__(256) void attn_kernel(
    const u16* __restrict__ qg, const u16* __restrict__ kg,
    const u16* __restrict__ vtg, u16* __restrict__ ctx) {
  __shared__ __align__(16) u16 KB[2][64 * 64];
  __shared__ __align__(16) u16 VB[2][64 * 64];
  __shared__ __align__(16) u16 Ps[64 * 64];

  const int bh = blockIdx.x;  // b*16 + h
  const int q0 = blockIdx.y * 64;
  const int t = threadIdx.x;
  const int wid = t >> 6, l = t & 63;
  const int quad = l >> 4, col = l & 15;
  const size_t base = (size_t)bh * SDIM * HD;

  // Q fragments (B-operand under swapped QK^T): lane col -> q row q0+16*wid+col
  bf16x8 aq[2];
  {
    const u16* qp = qg + base + (size_t)(q0 + 16 * wid + col) * HD + quad * 8;
    aq[0] = *(const bf16x8*)(qp);
    aq[1] = *(const bf16x8*)(qp + 32);
  }
  const int qi = q0 + 16 * wid + col;         // this lane's q row (mask/psum)
  const int qrow = q0 + 16 * wid + quad * 4;  // + r (oacc rows)

  // staging: row = (t>>3), chunk g = (t&7)^(row&7)
  const int srow = t >> 3;
  const int g = (t & 7) ^ (srow & 7);
  const u16* kptr = kg + base + (size_t)srow * HD + g * 8;
  const u16* vptr = vtg + base + (size_t)srow * SDIM + g * 8;
  const int wofs = (t & 192) << 4;

  auto stageK = [&](int kt, int buf) {
    char* d = (char*)KB[buf] + wofs;
    async_lds16(kptr + (size_t)(kt * 64) * HD, d);
    async_lds16(kptr + (size_t)(kt * 64 + 32) * HD, d + 4096);
  };
  auto stageV = [&](int kt, int buf) {
    char* d = (char*)VB[buf] + wofs;
    async_lds16(vptr + kt * 64, d);
    async_lds16(vptr + (size_t)32 * SDIM + kt * 64, d + 4096);
  };

  // swapped QK^T: A = K rows (k index), B = Q (col = q).
  // C: row = k-sub (quad*4+r), col = q-local (lane&15).
  auto qkt = [&](const u16* Kt, f32x4* sco) {
#pragma unroll
    for (int half = 0; half < 2; half++)
#pragma unroll
      for (int ct = 0; ct < 4; ct++) {
        int r = 16 * ct + col;
        int phys = (4 * half + quad) ^ (r & 7);
        bf16x8 kf = *(const bf16x8*)&Kt[r * 64 + phys * 8];
        sco[ct] = MFMA16(kf, aq[half], sco[ct]);
      }
  };

  // Ps byte offsets (16B-chunk XOR swizzle, precomputed; row stride 128 B)
  char* PsB = (char*)Ps;
  const int prow = 16 * wid + col;  // Ps row = q-local
  int wPs[4], rPs[2];
#pragma unroll
  for (int ct = 0; ct < 4; ct++)
    wPs[ct] = prow * 128 + (((2 * ct + (quad >> 1)) ^ (col & 7)) * 16) +
              (quad & 1) * 8;
#pragma unroll
  for (int half = 0; half < 2; half++)
    rPs[half] = prow * 128 + (((half * 4 + quad) ^ (col & 7)) * 16);

  float psum = 0.f;
  f32x4 oacc[4] = {};
  f32x4 scA[4] = {}, scB[4];

  // softmax(t): per lane 16 scores for q=qi, k = kt*64 + 16*ct + quad*4 + r.
  // pack pairs -> one ds_write_b64 per ct (4 consecutive k).
  auto smax = [&](int kt, f32x4 (&cur)[4], bool band) {
#pragma unroll
    for (int ct = 0; ct < 4; ct++) {
      float p[4];
#pragma unroll
      for (int r = 0; r < 4; r++) {
        float s = cur[ct][r];
        if (band) {
          int j = kt * 64 + 16 * ct + quad * 4 + r;
          if (j <= qi && j + 16 >= qi) s = -1.0e30f;
        }
        p[r] = __builtin_exp2f(s);
        psum += p[r];
      }
      u32 w0, w1;
      asm("v_cvt_pk_bf16_f32 %0, %1, %2" : "=v"(w0) : "v"(p[0]), "v"(p[1]));
      asm("v_cvt_pk_bf16_f32 %0, %1, %2" : "=v"(w1) : "v"(p[2]), "v"(p[3]));
      uint2 w;
      w.x = w0;
      w.y = w1;
      *(uint2*)(PsB + wPs[ct]) = w;
    }
  };

  auto pv = [&](const u16* Vt) {
#pragma unroll
    for (int half = 0; half < 2; half++) {
      bf16x8 pa = *(const bf16x8*)(PsB + rPs[half]);
#pragma unroll
      for (int dt = 0; dt < 4; dt++) {
        int vr = 16 * dt + col;
        int phys = (4 * half + quad) ^ (vr & 7);
        bf16x8 vf = *(const bf16x8*)&Vt[vr * 64 + phys * 8];
        oacc[dt] = MFMA16(pa, vf, oacc[dt]);
      }
    }
  };

  const int NT = SDIM / 64;  // 32 (even)

  // Per iter: barrier -> stage K(t+2),V(t+1) -> QK^T(t+1) [MFMA] ->
  // softmax(t) [VALU, overlaps MFMA] -> PV(t). ONE barrier/iter.
  auto body = [&](int kt, f32x4 (&cur)[4], f32x4 (&nxt)[4]) {
    __syncthreads();  // drains DMAs issued last iter: K(t+1), V(t)
    if (kt + 2 < NT) stageK(kt + 2, kt & 1);
    if (kt + 1 < NT) {
      stageV(kt + 1, (kt + 1) & 1);
#pragma unroll
      for (int ct = 0; ct < 4; ct++) nxt[ct] = f32x4{0.f, 0.f, 0.f, 0.f};
      qkt(KB[(kt + 1) & 1], nxt);
    }
    bool band = (kt * 64 <= q0 + 63) && (kt * 64 + 63 >= q0 - 16);
    smax(kt, cur, band);
    pv(VB[kt & 1]);
  };

  stageK(0, 0);
  stageV(0, 0);
  __syncthreads();
  qkt(KB[0], scA);
  stageK(1, 1);

#pragma unroll 1
  for (int kt = 0; kt < NT; kt += 2) {
    body(kt, scA, scB);
    body(kt + 1, scB, scA);
  }

  // reduce l across quads (k is lane-local; quads hold disjoint k subsets)
  psum += __shfl_xor(psum, 16, 64);
  psum += __shfl_xor(psum, 32, 64);

  // epilogue: ctx[b][s][h*64+d] = O / l   (bf16)
  const int b = bh >> 4, h = bh & 15;
  float linv[4];
#pragma unroll
  for (int r = 0; r < 4; r++)
    linv[r] = 1.0f / __shfl(psum, quad * 4 + r, 64);
#pragma unroll
  for (int dt = 0; dt < 4; dt++)
#pragma unroll
    for (int r = 0; r < 4; r++) {
      int qgl = qrow + r;
      int d = 16 * dt + col;
      ctx[((size_t)(b * SDIM + qgl)) * EDIM + h * HD + d] =
          f2bf(oacc[dt][r] * linv[r]);
    }
}

// ===================== GEMM2: output projection (128x128 tile, BK=64) ======
__global__ __launch_bounds__(256) void gemm_out_kernel(
    const u16* __restrict__ A, const u16* __restrict__ W,
    const float* __restrict__ bias, float* __restrict__ out) {
  __shared__ __align__(16) u16 As[128 * 64];
  __shared__ __align__(16) u16 Bs[128 * 64];
  const int m0 = blockIdx.x * 128, n0 = blockIdx.y * 128;
  const int t = threadIdx.x;
  const int l = t & 63;
  const int quad = l >> 4, col = l & 15;
  const int wid = t >> 6;
  const int mh = wid & 1, nh = wid >> 1;
  const int wofs = (t & 192) << 4;
  f32x4 acc[4][4] = {};
  const u16* Ab = A + (size_t)m0 * EDIM;
  const u16* Bb = W + (size_t)n0 * EDIM;
  char* AsB = (char*)As;
  char* BsB = (char*)Bs;

  for (int k0 = 0; k0 < EDIM; k0 += 64) {
    __syncthreads();
#pragma unroll
    for (int p = 0; p < 4; p++) {
      int idx = p * 256 + t;
      int row = idx >> 3;
      int gch = (idx & 7) ^ (row & 7);
      async_lds16(Ab + (size_t)row * EDIM + k0 + gch * 8, AsB + p * 4096 + wofs);
      async_lds16(Bb + (size_t)row * EDIM + k0 + gch * 8, BsB + p * 4096 + wofs);
    }
    __syncthreads();
#pragma unroll
    for (int kk = 0; kk < 2; kk++) {
      bf16x8 af[4], bfr[4];
#pragma unroll
      for (int i = 0; i < 4; i++) {
        int ra = 64 * mh + 16 * i + col;
        af[i] = *(const bf16x8*)&As[ra * 64 + (((kk * 4 + quad) ^ (ra & 7)) * 8)];
        int rb = 64 * nh + 16 * i + col;
        bfr[i] = *(const bf16x8*)&Bs[rb * 64 + (((kk * 4 + quad) ^ (rb & 7)) * 8)];
      }
#pragma unroll
      for (int i = 0; i < 4; i++)
#pragma unroll
        for (int j = 0; j < 4; j++)
          acc[i][j] = MFMA16(af[i], bfr[j], acc[i][j]);
    }
  }

#pragma unroll
  for (int i = 0; i < 4; i++)
#pragma unroll
    for (int j = 0; j < 4; j++)
#pragma unroll
      for (int r = 0; r < 4; r++) {
        int m = m0 + 64 * mh + 16 * i + quad * 4 + r;
        int n = n0 + 64 * nh + 16 * j + col;
        out[(size_t)m * EDIM + n] = acc[i][j][r] + bias[n];
      }
}

extern "C" void kernel_launch(void* const* d_in, const int* in_sizes, int n_in,
                              void* d_out, int out_size, void* d_ws,
                              size_t ws_size, hipStream_t stream) {
  const float* x = (const float*)d_in[0];
  const float* in_w = (const float*)d_in[2];
  const float* in_b = (const float*)d_in[3];
  const float* out_w = (const float*)d_in[4];
  const float* out_b = (const float*)d_in[5];
  float* out = (float*)d_out;

  char* ws = (char*)d_ws;
  u16* Xb  = (u16*)ws;                           // 8 MB (reused as ctx)
  u16* ctx = (u16*)ws;                           // alias of Xb
  u16* qb  = (u16*)(ws + (size_t)( 8 << 20));    // 8 MB (pre-scaled q)
  u16* kb  = (u16*)(ws + (size_t)(16 << 20));    // 8 MB
  u16* vtb = (u16*)(ws + (size_t)(24 << 20));    // 8 MB (transposed V)
  u16* Wib = (u16*)(ws + (size_t)(32 << 20));    // 6 MB
  u16* Wob = (u16*)(ws + (size_t)(38 << 20));    // 2 MB

  const int nX = MDIM * EDIM;
  const int nWi = 3 * EDIM * EDIM;
  const int nWo = EDIM * EDIM;
  cvt3_kernel<<<(nX + nWi + nWo) / 8 / 256, 256, 0, stream>>>(
      x, Xb, nX, in_w, Wib, nWi, out_w, Wob, nWo);

  gemm_qkv_kernel<<<dim3(MDIM / 128, 3 * EDIM / 128), 256, 0, stream>>>(
      Xb, Wib, in_b, qb, kb, vtb);
  attn_kernel<<<dim3(BDIM * HDIM, SDIM / 64), 256, 0, stream>>>(qb, kb, vtb, ctx);
  gemm_out_kernel<<<dim3(MDIM / 128, EDIM / 128), 256, 0, stream>>>(
      ctx, Wob, out_b, out);
}